// Round 2
// baseline (425.756 us; speedup 1.0000x reference)
//
#include <hip/hip_runtime.h>
#include <math.h>

#define B 128
#define M 32
#define P 8732
#define C 21
#define THRESH 0.5f
#define ALPHA 10.0f
#define TPB2 256  // k2: threads per block == priors per block

// ---------------- k1: best prior per object (obj_idx) -----------------------
// one wave per (b, m); lanes stride priors; argmax with first-index tie-break
__global__ __launch_bounds__(256) void k1_objargmax(
    const float* __restrict__ b_boxes, const float* __restrict__ priors,
    int* __restrict__ objidx) {
  int wid = threadIdx.x >> 6;
  int lane = threadIdx.x & 63;
  int task = blockIdx.x * 4 + wid;  // (b*M + m)
  if (task >= B * M) return;
  const float* bx = b_boxes + (size_t)task * 4;
  float x1 = bx[0], y1 = bx[1], x2 = bx[2], y2 = bx[3];
  float areaA = (x2 - x1) * (y2 - y1);
  float best = -1.0f;
  int bi = P;
  for (int p = lane; p < P; p += 64) {
    float4 pr = ((const float4*)priors)[p];
    float pw2 = pr.z * 0.5f, ph2 = pr.w * 0.5f;
    float iw = fminf(x2, pr.x + pw2) - fmaxf(x1, pr.x - pw2);
    float ih = fminf(y2, pr.y + ph2) - fmaxf(y1, pr.y - ph2);
    iw = fmaxf(iw, 0.0f);
    ih = fmaxf(ih, 0.0f);
    float inter = iw * ih;
    float iou = inter / (areaA + pr.z * pr.w - inter);
    if (iou > best) { best = iou; bi = p; }  // strict > keeps smallest p
  }
  for (int off = 32; off >= 1; off >>= 1) {
    float ov = __shfl_xor(best, off, 64);
    int oi = __shfl_xor(bi, off, 64);
    if (ov > best || (ov == best && oi < bi)) { best = ov; bi = oi; }
  }
  if (lane == 0) objidx[task] = bi;
}

// ---------------- k2: per-prior match + loc partial + CE --------------------
// Block covers TPB2 consecutive priors of one image. pred_cls slab for those
// priors is CONTIGUOUS in global (21*TPB2 floats) -> coalesced float4 staging
// into LDS, then per-thread CE from LDS (21t+c addressing: 2 lanes/bank, free).
__global__ __launch_bounds__(TPB2) void k2_perprior(
    const float* __restrict__ pred_loc, const float* __restrict__ pred_cls,
    const float* __restrict__ b_boxes, const int* __restrict__ b_labels,
    const float* __restrict__ priors, const int* __restrict__ objidx,
    float* __restrict__ accf, int* __restrict__ acci, int* __restrict__ nposimg,
    float* __restrict__ confneg) {
  int b = blockIdx.y;
  int p0 = blockIdx.x * TPB2;
  int nact = P - p0;
  if (nact > TPB2) nact = TPB2;
  int tid = threadIdx.x;

  __shared__ float sCls[TPB2 * C];  // 21504 B
  __shared__ float sx1[M], sy1[M], sx2[M], sy2[M], sarea[M];
  __shared__ int slab[M], sobj[M];

  if (tid < M) {
    int m = tid;
    float4 bx = ((const float4*)b_boxes)[b * M + m];
    sx1[m] = bx.x; sy1[m] = bx.y; sx2[m] = bx.z; sy2[m] = bx.w;
    sarea[m] = (bx.z - bx.x) * (bx.w - bx.y);
    slab[m] = b_labels[b * M + m];
    sobj[m] = objidx[b * M + m];
  }
  // coalesced staging of pred_cls slab: nact*21 floats, divisible by 4,
  // 16B-aligned (b*P*C and p0*C are multiples of 4 elements)
  {
    const float4* src = (const float4*)(pred_cls + ((size_t)b * P + p0) * C);
    int nf4 = nact * C / 4;
    for (int i = tid; i < nf4; i += TPB2) ((float4*)sCls)[i] = src[i];
  }
  __syncthreads();

  float locpart = 0.0f, cepospart = 0.0f;
  int npos = 0;
  if (tid < nact) {
    int p = p0 + tid;
    float4 pr = ((const float4*)priors)[p];
    float pw2 = pr.z * 0.5f, ph2 = pr.w * 0.5f;
    float px1 = pr.x - pw2, py1 = pr.y - ph2;
    float px2 = pr.x + pw2, py2 = pr.y + ph2;
    float areaP = pr.z * pr.w;
    float best = -1.0f;
    int bm = 0;
#pragma unroll
    for (int m = 0; m < M; m++) {
      float iw = fminf(sx2[m], px2) - fmaxf(sx1[m], px1);
      float ih = fminf(sy2[m], py2) - fmaxf(sy1[m], py1);
      iw = fmaxf(iw, 0.0f);
      ih = fmaxf(ih, 0.0f);
      float inter = iw * ih;
      float iou = inter / (sarea[m] + areaP - inter);
      if (sobj[m] == p) iou = 1.0f;            // forced best-prior-per-object
      if (iou > best) { best = iou; bm = m; }  // first max (ascending m)
    }
    bool pos = best >= THRESH;
    int cls = pos ? slab[bm] : 0;

    // encode matched box vs prior
    float bx1 = sx1[bm], by1 = sy1[bm], bx2 = sx2[bm], by2 = sy2[bm];
    float cx = (bx1 + bx2) * 0.5f, cy = (by1 + by2) * 0.5f;
    float w = bx2 - bx1, h = by2 - by1;
    float g0 = (cx - pr.x) * 10.0f / pr.z;
    float g1 = (cy - pr.y) * 10.0f / pr.w;
    float g2 = logf(w / pr.z) * 5.0f;
    float g3 = logf(h / pr.w) * 5.0f;

    float4 pl = ((const float4*)pred_loc)[(size_t)b * P + p];
    if (pos) {
      locpart = fabsf(pl.x - g0) + fabsf(pl.y - g1) +
                fabsf(pl.z - g2) + fabsf(pl.w - g3);
      npos = 1;
    }

    // cross-entropy via stabilized logsumexp over 21 classes (from LDS)
    const float* v = &sCls[tid * C];
    float mx = v[0];
#pragma unroll
    for (int c = 1; c < C; c++) mx = fmaxf(mx, v[c]);
    float se = 0.0f;
#pragma unroll
    for (int c = 0; c < C; c++) se += expf(v[c] - mx);
    float lse = mx + logf(se);
    float ce = lse - v[cls];

    confneg[(size_t)b * P + p] = pos ? 0.0f : ce;
    cepospart = pos ? ce : 0.0f;
  }

  // block reduction -> global atomics
  for (int off = 32; off >= 1; off >>= 1) {
    locpart += __shfl_down(locpart, off, 64);
    cepospart += __shfl_down(cepospart, off, 64);
    npos += __shfl_down(npos, off, 64);
  }
  __shared__ float rloc[4], rce[4];
  __shared__ int rnp[4];
  int wid = tid >> 6;
  if ((tid & 63) == 0) { rloc[wid] = locpart; rce[wid] = cepospart; rnp[wid] = npos; }
  __syncthreads();
  if (tid == 0) {
    float l = rloc[0] + rloc[1] + rloc[2] + rloc[3];
    float ce = rce[0] + rce[1] + rce[2] + rce[3];
    int n = rnp[0] + rnp[1] + rnp[2] + rnp[3];
    atomicAdd(&accf[0], l);
    atomicAdd(&accf[1], ce);
    if (n) {
      atomicAdd(&nposimg[b], n);
      atomicAdd(&acci[3], n);  // global n_pos_total
    }
  }
}

// ---------------- k3: per-image exact top-K sum via radix-256 select --------
// Values are IEEE fp32 >= 0 -> bit pattern is order-monotone. 4 MSB-first
// passes of 8 bits find the exact K-th-largest value tau; then
// hard = sum(v>tau) + (K - cnt_gt)*tau  (exact tie handling, same as sort).
// Last block to finish computes the final 3 scalars (k4 fused away).
__global__ __launch_bounds__(1024) void k3_hardneg(
    const float* __restrict__ confneg, const int* __restrict__ nposimg,
    float* __restrict__ accf, int* __restrict__ acci,
    float* __restrict__ out) {
  int b = blockIdx.x;
  int tid = threadIdx.x;
  __shared__ float s[P];       // ~35 KB
  __shared__ int hist[256];
  __shared__ int sdig, scum;
  __shared__ float rsum[16];
  __shared__ int rcnt[16];

  const float* row = confneg + (size_t)b * P;
  for (int i = tid; i < P; i += 1024) s[i] = row[i];
  int K = nposimg[b] * 3;
  if (K > P) K = P;
  __syncthreads();

  unsigned pfx = 0;
  int Krem = K;
  for (int pass = 3; pass >= 0; --pass) {
    int sh = pass * 8;
    if (tid < 256) hist[tid] = 0;
    __syncthreads();
    unsigned himask = (pass == 3) ? 0u : (0xFFFFFFFFu << (sh + 8));
    for (int i = tid; i < P; i += 1024) {
      unsigned ub = __float_as_uint(s[i]);
      if ((ub & himask) == pfx) atomicAdd(&hist[(ub >> sh) & 255], 1);
    }
    __syncthreads();
    if (tid == 0) {
      int c = 0, d = 255;
      for (; d > 0; --d) {
        c += hist[d];
        if (c >= Krem) break;
      }
      if (c < Krem) c += hist[0];  // d==0 fallthrough
      sdig = d;
      scum = c - hist[d];  // count strictly above chosen digit
    }
    __syncthreads();
    pfx |= ((unsigned)sdig) << sh;
    Krem -= scum;
    __syncthreads();
  }
  float tau = __uint_as_float(pfx);  // exact K-th largest value

  float sum = 0.0f;
  int cgt = 0;
  for (int i = tid; i < P; i += 1024) {
    float v = s[i];
    if (v > tau) { sum += v; cgt++; }
  }
  for (int off = 32; off >= 1; off >>= 1) {
    sum += __shfl_down(sum, off, 64);
    cgt += __shfl_down(cgt, off, 64);
  }
  int wid = tid >> 6;
  if ((tid & 63) == 0) { rsum[wid] = sum; rcnt[wid] = cgt; }
  __syncthreads();
  if (tid == 0) {
    float stot = 0.0f;
    int ctot = 0;
#pragma unroll
    for (int w = 0; w < 16; w++) { stot += rsum[w]; ctot += rcnt[w]; }
    float hard = stot + (float)(K - ctot) * tau;
    atomicAdd(&accf[2], hard);
    __threadfence();
    int prev = atomicAdd(&acci[4], 1);
    if (prev == B - 1) {  // last block: finalize (fused k4)
      __threadfence();
      float loc_sum = atomicAdd(&accf[0], 0.0f);
      float ce_pos = atomicAdd(&accf[1], 0.0f);
      float hardtot = atomicAdd(&accf[2], 0.0f);
      int nt = atomicAdd(&acci[3], 0);
      float nf = (float)nt;
      float loc = ALPHA * loc_sum / (nf * 4.0f);
      float conf = (hardtot + ce_pos) / nf;
      out[0] = conf + loc;
      out[1] = loc;
      out[2] = conf;
    }
  }
}

extern "C" void kernel_launch(void* const* d_in, const int* in_sizes, int n_in,
                              void* d_out, int out_size, void* d_ws, size_t ws_size,
                              hipStream_t stream) {
  (void)in_sizes; (void)n_in; (void)out_size; (void)ws_size;
  const float* pred_loc = (const float*)d_in[0];
  const float* pred_cls = (const float*)d_in[1];
  const float* b_boxes = (const float*)d_in[2];
  const int* b_labels = (const int*)d_in[3];
  const float* priors = (const float*)d_in[4];
  float* out = (float*)d_out;

  // workspace layout (4-byte units):
  // [0..2] accf: loc_sum, ce_pos, hard_neg   [3] npos_total (int)
  // [4] done counter (int)                   [8..8+B) nposimg (int)
  // [8+B..8+B+B*M) objidx (int)              then confneg (B*P floats)
  float* accf = (float*)d_ws;
  int* acci = (int*)d_ws;
  int* nposimg = acci + 8;
  int* objidx = acci + 8 + B;
  float* confneg = (float*)d_ws + 8 + B + B * M;

  hipMemsetAsync(d_ws, 0, (8 + B) * sizeof(float), stream);

  k1_objargmax<<<(B * M + 3) / 4, 256, 0, stream>>>(b_boxes, priors, objidx);
  dim3 g2((P + TPB2 - 1) / TPB2, B);
  k2_perprior<<<g2, TPB2, 0, stream>>>(pred_loc, pred_cls, b_boxes, b_labels,
                                       priors, objidx, accf, acci, nposimg, confneg);
  k3_hardneg<<<B, 1024, 0, stream>>>(confneg, nposimg, accf, acci, out);
}